// Round 3
// baseline (709.957 us; speedup 1.0000x reference)
//
#include <hip/hip_runtime.h>
#include <math.h>

#define NPTS 262144
#define BB 8
#define HH 512
#define WW 512
#define EPSV 1e-5f

typedef short short8v __attribute__((ext_vector_type(8)));
typedef short short4v __attribute__((ext_vector_type(4)));
typedef float float4v __attribute__((ext_vector_type(4)));
typedef unsigned short ushort;
typedef ushort ushort8v __attribute__((ext_vector_type(8)));

static __device__ __forceinline__ ushort f2bf(float f) {
  union { float f; unsigned u; } v;
  v.f = f;
  unsigned r = v.u + 0x7fffu + ((v.u >> 16) & 1u);  // round-to-nearest-even
  return (ushort)(r >> 16);
}

static __device__ __forceinline__ float bf2f(ushort h) {
  union { unsigned u; float f; } v;
  v.u = ((unsigned)h) << 16;
  return v.f;
}

// ---------------- rulebook (transposed: nbrT[tap][pt]) ----------------

__global__ __launch_bounds__(256) void k_scatter(const int* __restrict__ idx,
                                                 int* __restrict__ grid) {
  int i = blockIdx.x * 256 + threadIdx.x;
  int b = idx[i * 3 + 0], y = idx[i * 3 + 1], x = idx[i * 3 + 2];
  grid[(b * HH + y) * WW + x] = i;
}

__global__ __launch_bounds__(256) void k_rulebook(const int* __restrict__ idx,
                                                  const int* __restrict__ grid,
                                                  int* __restrict__ nbrT) {
  int i = blockIdx.x * 256 + threadIdx.x;
  int b = idx[i * 3 + 0], y = idx[i * 3 + 1], x = idx[i * 3 + 2];
  int t = 0;
  #pragma unroll
  for (int dy = -1; dy <= 1; ++dy) {
    #pragma unroll
    for (int dx = -1; dx <= 1; ++dx) {
      int ny = y + dy, nx = x + dx;
      int v = -1;
      if (ny >= 0 && ny < HH && nx >= 0 && nx < WW)
        v = grid[(b * HH + ny) * WW + nx];
      nbrT[(size_t)t * NPTS + i] = v;
      ++t;
    }
  }
}

// ---------------- batchnorm stats (feats, fp32, CI=64) ----------------

__global__ __launch_bounds__(256) void k_stats64(const float* __restrict__ x,
                                                 float* __restrict__ sum,
                                                 float* __restrict__ ssum) {
  __shared__ float red_s[4][64];
  __shared__ float red_q[4][64];
  const int tid = threadIdx.x;
  const int lane = tid & 63;
  const int wave = tid >> 6;
  const int c4 = lane & 15;
  const int rq = lane >> 4;
  long long base = (long long)blockIdx.x * 256;
  float s0 = 0.f, s1 = 0.f, s2 = 0.f, s3 = 0.f;
  float q0 = 0.f, q1 = 0.f, q2 = 0.f, q3 = 0.f;
  for (int r = wave * 4 + rq; r < 256; r += 16) {
    float4 v = *(const float4*)(x + (base + r) * 64 + c4 * 4);
    s0 += v.x; s1 += v.y; s2 += v.z; s3 += v.w;
    q0 += v.x * v.x; q1 += v.y * v.y; q2 += v.z * v.z; q3 += v.w * v.w;
  }
  s0 += __shfl_xor(s0, 16, 64); s0 += __shfl_xor(s0, 32, 64);
  s1 += __shfl_xor(s1, 16, 64); s1 += __shfl_xor(s1, 32, 64);
  s2 += __shfl_xor(s2, 16, 64); s2 += __shfl_xor(s2, 32, 64);
  s3 += __shfl_xor(s3, 16, 64); s3 += __shfl_xor(s3, 32, 64);
  q0 += __shfl_xor(q0, 16, 64); q0 += __shfl_xor(q0, 32, 64);
  q1 += __shfl_xor(q1, 16, 64); q1 += __shfl_xor(q1, 32, 64);
  q2 += __shfl_xor(q2, 16, 64); q2 += __shfl_xor(q2, 32, 64);
  q3 += __shfl_xor(q3, 16, 64); q3 += __shfl_xor(q3, 32, 64);
  if (rq == 0) {
    red_s[wave][c4 * 4 + 0] = s0; red_s[wave][c4 * 4 + 1] = s1;
    red_s[wave][c4 * 4 + 2] = s2; red_s[wave][c4 * 4 + 3] = s3;
    red_q[wave][c4 * 4 + 0] = q0; red_q[wave][c4 * 4 + 1] = q1;
    red_q[wave][c4 * 4 + 2] = q2; red_q[wave][c4 * 4 + 3] = q3;
  }
  __syncthreads();
  if (tid < 64) {
    float ts = red_s[0][tid] + red_s[1][tid] + red_s[2][tid] + red_s[3][tid];
    float tq = red_q[0][tid] + red_q[1][tid] + red_q[2][tid] + red_q[3][tid];
    atomicAdd(&sum[tid], ts);
    atomicAdd(&ssum[tid], tq);
  }
}

template <int CI>
__global__ void k_finalize(const float* __restrict__ sum, const float* __restrict__ ssum,
                           const float* __restrict__ gam, const float* __restrict__ bet,
                           float* __restrict__ sc, float* __restrict__ sh) {
  int c = threadIdx.x;
  if (c < CI) {
    float m = sum[c] * (1.f / NPTS);
    float v = ssum[c] * (1.f / NPTS) - m * m;
    float s = gam[c] * rsqrtf(v + EPSV);
    sc[c] = s;
    sh[c] = bet[c] - m * s;
  }
}

// ---------------- normalize passes (apply BN+ReLU once, not 9x) ----------------

// feats fp32 [N][64] -> bf16 [N][64]
__global__ __launch_bounds__(256) void k_norm1(const float* __restrict__ x,
                                               const float* __restrict__ sc,
                                               const float* __restrict__ sh,
                                               ushort* __restrict__ y) {
  long long i = ((long long)blockIdx.x * 256 + threadIdx.x) * 8;
  int c = (int)(i & 63);
  float4 a = *(const float4*)(x + i);
  float4 b = *(const float4*)(x + i + 4);
  float4 s0 = *(const float4*)(sc + c);
  float4 s1 = *(const float4*)(sc + c + 4);
  float4 h0 = *(const float4*)(sh + c);
  float4 h1 = *(const float4*)(sh + c + 4);
  ushort8v o;
  o[0] = f2bf(fmaxf(a.x * s0.x + h0.x, 0.f));
  o[1] = f2bf(fmaxf(a.y * s0.y + h0.y, 0.f));
  o[2] = f2bf(fmaxf(a.z * s0.z + h0.z, 0.f));
  o[3] = f2bf(fmaxf(a.w * s0.w + h0.w, 0.f));
  o[4] = f2bf(fmaxf(b.x * s1.x + h1.x, 0.f));
  o[5] = f2bf(fmaxf(b.y * s1.y + h1.y, 0.f));
  o[6] = f2bf(fmaxf(b.z * s1.z + h1.z, 0.f));
  o[7] = f2bf(fmaxf(b.w * s1.w + h1.w, 0.f));
  *(ushort8v*)(y + i) = o;
}

// in-place bf16 [N][128] normalize+relu
__global__ __launch_bounds__(256) void k_norm2(ushort* __restrict__ x,
                                               const float* __restrict__ sc,
                                               const float* __restrict__ sh) {
  long long i = ((long long)blockIdx.x * 256 + threadIdx.x) * 8;
  int c = (int)(i & 127);
  ushort8v v = *(const ushort8v*)(x + i);
  float4 s0 = *(const float4*)(sc + c);
  float4 s1 = *(const float4*)(sc + c + 4);
  float4 h0 = *(const float4*)(sh + c);
  float4 h1 = *(const float4*)(sh + c + 4);
  ushort8v o;
  o[0] = f2bf(fmaxf(bf2f(v[0]) * s0.x + h0.x, 0.f));
  o[1] = f2bf(fmaxf(bf2f(v[1]) * s0.y + h0.y, 0.f));
  o[2] = f2bf(fmaxf(bf2f(v[2]) * s0.z + h0.z, 0.f));
  o[3] = f2bf(fmaxf(bf2f(v[3]) * s0.w + h0.w, 0.f));
  o[4] = f2bf(fmaxf(bf2f(v[4]) * s1.x + h1.x, 0.f));
  o[5] = f2bf(fmaxf(bf2f(v[5]) * s1.y + h1.y, 0.f));
  o[6] = f2bf(fmaxf(bf2f(v[6]) * s1.z + h1.z, 0.f));
  o[7] = f2bf(fmaxf(bf2f(v[7]) * s1.w + h1.w, 0.f));
  *(ushort8v*)(x + i) = o;
}

// ---------------- weight prep: fp32 [taps][ci][128] -> bf16 [taps][128][ci] ----

__global__ __launch_bounds__(256) void k_wprep(const float* __restrict__ w,
                                               ushort* __restrict__ wt,
                                               int taps, int ci) {
  int i = blockIdx.x * 256 + threadIdx.x;
  int total = taps * ci * 128;
  if (i < total) {
    int t = i / (ci * 128);
    int rem = i - t * ci * 128;
    int c = rem >> 7;
    int o = rem & 127;
    wt[((size_t)t * 128 + o) * ci + c] = f2bf(w[i]);
  }
}

// ---------------- direct-fragment MFMA conv (no LDS, no barriers) ----------------
// A-frag for mfma 16x16x32: lane(fm,fq) = 16B at src[nid[row]]*CI + kc*32 + fq*8.
// Rows are gathered via nbrT; input must be pre-normalized bf16. B-frags come
// straight from the 32KB/tap transposed weight tile (L1-resident, shared by
// all blocks). EPI=1: fused bn-stats of stored bf16. EPI=2: fused batch pool.

template <int CI, typename DstT, int EPI>
__global__ __launch_bounds__(256) void k_convd(const ushort* __restrict__ src,
                                               const int* __restrict__ nbrT,
                                               const ushort* __restrict__ wt,
                                               DstT* __restrict__ dst,
                                               float* __restrict__ e0,
                                               float* __restrict__ e1) {
  const int tid = threadIdx.x;
  const int base = blockIdx.x * 128;
  const int lane = tid & 63;
  const int wave = tid >> 6;
  const int wm = wave & 1, wn = wave >> 1;
  const int m_base = wm * 64, n_base = wn * 64;
  const int fm = lane & 15;
  const int fq = lane >> 4;
  const int koff = fq * 8;

  float4v acc[4][4];
  #pragma unroll
  for (int i = 0; i < 4; ++i)
    #pragma unroll
    for (int j = 0; j < 4; ++j) acc[i][j] = (float4v){0.f, 0.f, 0.f, 0.f};

  const int* nrow = nbrT + base + m_base + fm;

  for (int k = 0; k < 9; ++k) {
    int nid0 = nrow[(size_t)k * NPTS + 0];
    int nid1 = nrow[(size_t)k * NPTS + 16];
    int nid2 = nrow[(size_t)k * NPTS + 32];
    int nid3 = nrow[(size_t)k * NPTS + 48];
    const ushort* wrow = wt + ((size_t)k * 128 + n_base + fm) * CI + koff;
    #pragma unroll
    for (int kc = 0; kc < CI / 32; ++kc) {
      short8v bfr[4];
      #pragma unroll
      for (int ni = 0; ni < 4; ++ni)
        bfr[ni] = *(const short8v*)(wrow + ni * 16 * CI + kc * 32);
      const short8v z = {0, 0, 0, 0, 0, 0, 0, 0};
      short8v a0 = (nid0 >= 0) ? *(const short8v*)(src + (size_t)nid0 * CI + kc * 32 + koff) : z;
      short8v a1 = (nid1 >= 0) ? *(const short8v*)(src + (size_t)nid1 * CI + kc * 32 + koff) : z;
      short8v a2 = (nid2 >= 0) ? *(const short8v*)(src + (size_t)nid2 * CI + kc * 32 + koff) : z;
      short8v a3 = (nid3 >= 0) ? *(const short8v*)(src + (size_t)nid3 * CI + kc * 32 + koff) : z;
      #pragma unroll
      for (int ni = 0; ni < 4; ++ni) acc[0][ni] = __builtin_amdgcn_mfma_f32_16x16x32_bf16(a0, bfr[ni], acc[0][ni], 0, 0, 0);
      #pragma unroll
      for (int ni = 0; ni < 4; ++ni) acc[1][ni] = __builtin_amdgcn_mfma_f32_16x16x32_bf16(a1, bfr[ni], acc[1][ni], 0, 0, 0);
      #pragma unroll
      for (int ni = 0; ni < 4; ++ni) acc[2][ni] = __builtin_amdgcn_mfma_f32_16x16x32_bf16(a2, bfr[ni], acc[2][ni], 0, 0, 0);
      #pragma unroll
      for (int ni = 0; ni < 4; ++ni) acc[3][ni] = __builtin_amdgcn_mfma_f32_16x16x32_bf16(a3, bfr[ni], acc[3][ni], 0, 0, 0);
    }
  }

  // ---- epilogue: C/D layout col=lane&15, row=quad*4+reg ----
  float es[4], ess[4];
  if constexpr (EPI) {
    #pragma unroll
    for (int ni = 0; ni < 4; ++ni) { es[ni] = 0.f; ess[ni] = 0.f; }
  }
  #pragma unroll
  for (int mi = 0; mi < 4; ++mi) {
    #pragma unroll
    for (int ni = 0; ni < 4; ++ni) {
      int pt = base + m_base + mi * 16 + fq * 4;
      int co = n_base + ni * 16 + fm;
      float4v c = acc[mi][ni];
      #pragma unroll
      for (int r = 0; r < 4; ++r) {
        if constexpr (sizeof(DstT) == 4) {
          ((float*)dst)[(size_t)(pt + r) * 128 + co] = c[r];
          if constexpr (EPI == 2) es[ni] += c[r];
        } else {
          ushort h = f2bf(c[r]);
          ((ushort*)dst)[(size_t)(pt + r) * 128 + co] = h;
          if constexpr (EPI == 1) {
            float v = bf2f(h);
            es[ni] += v;
            ess[ni] += v * v;
          }
        }
      }
    }
  }

  if constexpr (EPI) {
    #pragma unroll
    for (int ni = 0; ni < 4; ++ni) {
      float s = es[ni];
      s += __shfl_xor(s, 16, 64);
      s += __shfl_xor(s, 32, 64);
      float q = 0.f;
      if constexpr (EPI == 1) {
        q = ess[ni];
        q += __shfl_xor(q, 16, 64);
        q += __shfl_xor(q, 32, 64);
      }
      if (fq == 0) {
        int co = n_base + ni * 16 + fm;
        if constexpr (EPI == 1) {
          atomicAdd(&e0[co], s);
          atomicAdd(&e1[co], q);
        } else {
          int b = base >> 15;
          atomicAdd(&e0[b * 128 + co], s);
        }
      }
    }
  }
}

// ---------------- legacy LDS-staged conv (fallback path + skip GEMM) ----------------

template <typename SrcT, typename DstT, int CI, int TAPS, bool ACT, int EPI>
__global__ __launch_bounds__(256) void k_conv(const SrcT* __restrict__ src,
                                              const float* __restrict__ scale,
                                              const float* __restrict__ shift,
                                              const int* __restrict__ nbrT,
                                              const ushort* __restrict__ wt,
                                              DstT* __restrict__ dst,
                                              float* __restrict__ e0,
                                              float* __restrict__ e1) {
  constexpr int SA = CI + 8;
  __shared__ ushort As[128 * SA];
  __shared__ ushort Bs[128 * SA];
  __shared__ float s_sc[CI], s_sh[CI];

  const int tid = threadIdx.x;
  const int base = blockIdx.x * 128;
  const int lane = tid & 63;
  const int wave = tid >> 6;
  const int wm = wave & 1, wn = wave >> 1;
  const int m_base = wm * 64, n_base = wn * 64;
  const int fm = lane & 15;
  const int fq = lane >> 4;

  if constexpr (ACT) {
    for (int c = tid; c < CI; c += 256) {
      s_sc[c] = scale[c];
      s_sh[c] = shift[c];
    }
  }
  __syncthreads();

  float4v acc[4][4];
  #pragma unroll
  for (int i = 0; i < 4; ++i)
    #pragma unroll
    for (int j = 0; j < 4; ++j) acc[i][j] = (float4v){0.f, 0.f, 0.f, 0.f};

  const int srow_i = tid >> 1;
  const int shalf = tid & 1;
  const int c0 = shalf * (CI / 2);

  for (int k = 0; k < TAPS; ++k) {
    if (k) __syncthreads();

    int nid;
    if constexpr (TAPS == 1) {
      nid = base + srow_i;
    } else {
      nid = nbrT[(size_t)k * NPTS + base + srow_i];
    }
    ushort* arow = &As[srow_i * SA + c0];
    if (nid >= 0) {
      const SrcT* gsrc = src + (size_t)nid * CI + c0;
      if constexpr (sizeof(SrcT) == 4) {
        #pragma unroll
        for (int j = 0; j < CI / 2; j += 4) {
          float4 v = *(const float4*)((const float*)gsrc + j);
          if constexpr (ACT) {
            int c = c0 + j;
            v.x = fmaxf(v.x * s_sc[c + 0] + s_sh[c + 0], 0.f);
            v.y = fmaxf(v.y * s_sc[c + 1] + s_sh[c + 1], 0.f);
            v.z = fmaxf(v.z * s_sc[c + 2] + s_sh[c + 2], 0.f);
            v.w = fmaxf(v.w * s_sc[c + 3] + s_sh[c + 3], 0.f);
          }
          short4v o = {(short)f2bf(v.x), (short)f2bf(v.y), (short)f2bf(v.z), (short)f2bf(v.w)};
          *(short4v*)(arow + j) = o;
        }
      } else {
        #pragma unroll
        for (int j = 0; j < CI / 2; j += 8) {
          ushort8v raw = *(const ushort8v*)((const ushort*)gsrc + j);
          short8v o;
          #pragma unroll
          for (int e = 0; e < 8; ++e) {
            float f = bf2f(raw[e]);
            if constexpr (ACT) {
              int c = c0 + j + e;
              f = fmaxf(f * s_sc[c] + s_sh[c], 0.f);
            }
            o[e] = (short)f2bf(f);
          }
          *(short8v*)(arow + j) = o;
        }
      }
    } else {
      #pragma unroll
      for (int j = 0; j < CI / 2; j += 4)
        *(short4v*)(arow + j) = (short4v){0, 0, 0, 0};
    }

    {
      const ushort* wrow = wt + ((size_t)k * 128 + srow_i) * CI + c0;
      ushort* brow = &Bs[srow_i * SA + c0];
      #pragma unroll
      for (int j = 0; j < CI / 2; j += 8)
        *(uint4*)(brow + j) = *(const uint4*)(wrow + j);
    }
    __syncthreads();

    #pragma unroll
    for (int kc = 0; kc < CI / 32; ++kc) {
      short8v af[4], bf[4];
      #pragma unroll
      for (int mi = 0; mi < 4; ++mi)
        af[mi] = *(const short8v*)(&As[(m_base + mi * 16 + fm) * SA + kc * 32 + fq * 8]);
      #pragma unroll
      for (int ni = 0; ni < 4; ++ni)
        bf[ni] = *(const short8v*)(&Bs[(n_base + ni * 16 + fm) * SA + kc * 32 + fq * 8]);
      #pragma unroll
      for (int mi = 0; mi < 4; ++mi)
        #pragma unroll
        for (int ni = 0; ni < 4; ++ni)
          acc[mi][ni] = __builtin_amdgcn_mfma_f32_16x16x32_bf16(af[mi], bf[ni], acc[mi][ni], 0, 0, 0);
    }
  }

  float es[4], ess[4];
  if constexpr (EPI) {
    #pragma unroll
    for (int ni = 0; ni < 4; ++ni) { es[ni] = 0.f; ess[ni] = 0.f; }
  }
  #pragma unroll
  for (int mi = 0; mi < 4; ++mi) {
    #pragma unroll
    for (int ni = 0; ni < 4; ++ni) {
      int pt = base + m_base + mi * 16 + fq * 4;
      int co = n_base + ni * 16 + fm;
      float4v c = acc[mi][ni];
      #pragma unroll
      for (int r = 0; r < 4; ++r) {
        if constexpr (sizeof(DstT) == 4) {
          ((float*)dst)[(size_t)(pt + r) * 128 + co] = c[r];
          if constexpr (EPI == 2) es[ni] += c[r];
        } else {
          ushort h = f2bf(c[r]);
          ((ushort*)dst)[(size_t)(pt + r) * 128 + co] = h;
          if constexpr (EPI == 1) {
            float v = bf2f(h);
            es[ni] += v;
            ess[ni] += v * v;
          }
        }
      }
    }
  }

  if constexpr (EPI) {
    #pragma unroll
    for (int ni = 0; ni < 4; ++ni) {
      float s = es[ni];
      s += __shfl_xor(s, 16, 64);
      s += __shfl_xor(s, 32, 64);
      float q = 0.f;
      if constexpr (EPI == 1) {
        q = ess[ni];
        q += __shfl_xor(q, 16, 64);
        q += __shfl_xor(q, 32, 64);
      }
      if (fq == 0) {
        int co = n_base + ni * 16 + fm;
        if constexpr (EPI == 1) {
          atomicAdd(&e0[co], s);
          atomicAdd(&e1[co], q);
        } else {
          int b = base >> 15;
          atomicAdd(&e0[b * 128 + co], s);
        }
      }
    }
  }
}

// ---------------- SE / final ----------------

__global__ __launch_bounds__(256) void k_se(const float* __restrict__ pooled,
                                            const float* __restrict__ fc1w,
                                            const float* __restrict__ fc1b,
                                            const float* __restrict__ fc2w,
                                            const float* __restrict__ fc2b,
                                            float* __restrict__ se) {
  __shared__ float h[8][32];
  int tid = threadIdx.x;
  int b = tid >> 5, j = tid & 31;
  float s = fc1b[j];
  for (int c = 0; c < 128; ++c)
    s += pooled[b * 128 + c] * (1.f / 32768.f) * fc1w[j * 128 + c];
  h[b][j] = fmaxf(s, 0.f);
  __syncthreads();
  for (int t = tid; t < 1024; t += 256) {
    int bb = t >> 7, c = t & 127;
    float s2 = fc2b[c];
    #pragma unroll
    for (int jj = 0; jj < 32; ++jj) s2 += h[bb][jj] * fc2w[c * 32 + jj];
    se[t] = 1.f / (1.f + expf(-s2));
  }
}

__global__ __launch_bounds__(256) void k_final(float* __restrict__ out,
                                               const ushort* __restrict__ id,
                                               const float* __restrict__ se) {
  long long i = ((long long)blockIdx.x * 256 + threadIdx.x) * 4;
  int co = (int)(i & 127);
  long long rowi = i >> 7;
  int b = (int)(rowi >> 15);
  float4 o = *(const float4*)(out + i);
  ushort dh[4];
  *(uint2*)dh = *(const uint2*)(id + i);
  float4 s = *(const float4*)(se + b * 128 + co);
  o.x = o.x * s.x + bf2f(dh[0]);
  o.y = o.y * s.y + bf2f(dh[1]);
  o.z = o.z * s.z + bf2f(dh[2]);
  o.w = o.w * s.w + bf2f(dh[3]);
  *(float4*)(out + i) = o;
}

// ---------------- launch ----------------

extern "C" void kernel_launch(void* const* d_in, const int* in_sizes, int n_in,
                              void* d_out, int out_size, void* d_ws, size_t ws_size,
                              hipStream_t stream) {
  const float* feats = (const float*)d_in[0];
  const int* indices = (const int*)d_in[1];
  const float* bn1_g = (const float*)d_in[2];
  const float* bn1_b = (const float*)d_in[3];
  const float* w1    = (const float*)d_in[4];
  const float* bn2_g = (const float*)d_in[5];
  const float* bn2_b = (const float*)d_in[6];
  const float* w2    = (const float*)d_in[7];
  const float* fc1w  = (const float*)d_in[8];
  const float* fc1b  = (const float*)d_in[9];
  const float* fc2w  = (const float*)d_in[10];
  const float* fc2b  = (const float*)d_in[11];
  const float* wskip = (const float*)d_in[12];
  float* out = (float*)d_out;

  char* p = (char*)d_ws;
  int* nbrT = (int*)p;      p += (size_t)NPTS * 9 * 4;        // 9.44 MB
  float* stats = (float*)p; p += 4096 * 4;                    // 16 KB
  ushort* wt1 = (ushort*)p; p += (size_t)9 * 128 * 64 * 2;    // 144 KB
  ushort* wt2 = (ushort*)p; p += (size_t)9 * 128 * 128 * 2;   // 288 KB
  ushort* wts = (ushort*)p; p += (size_t)128 * 64 * 2;        // 16 KB
  p = (char*)(((size_t)p + 255) & ~(size_t)255);

  float* sum1 = stats, *ss1 = stats + 64, *sc1 = stats + 128, *sh1 = stats + 192;
  float* sum2 = stats + 256, *ss2 = stats + 384, *sc2 = stats + 512, *sh2 = stats + 640;
  float* pooled = stats + 768;
  float* se = stats + 1792;

  // new path needs: region1 = max(grid 8MB, featsn 33.5MB) + out1 67MB
  size_t fixed = (size_t)(p - (char*)d_ws);
  size_t need_new = fixed + (size_t)NPTS * 64 * 2 + (size_t)NPTS * 128 * 2;
  bool big = ws_size >= need_new;

  hipMemsetAsync(stats, 0, 4096 * 4, stream);

  if (big) {
    // region1: first serves as grid (8MB), later as featsn (33.5MB bf16)
    int* grid_i = (int*)p;
    ushort* featsn = (ushort*)p;
    ushort* out1 = (ushort*)(p + (size_t)NPTS * 64 * 2);  // also reused as id

    hipMemsetAsync(grid_i, 0xFF, (size_t)BB * HH * WW * 4, stream);
    k_scatter<<<NPTS / 256, 256, 0, stream>>>(indices, grid_i);
    k_rulebook<<<NPTS / 256, 256, 0, stream>>>(indices, grid_i, nbrT);

    k_wprep<<<(9 * 64 * 128 + 255) / 256, 256, 0, stream>>>(w1, wt1, 9, 64);
    k_wprep<<<(9 * 128 * 128 + 255) / 256, 256, 0, stream>>>(w2, wt2, 9, 128);
    k_wprep<<<(64 * 128 + 255) / 256, 256, 0, stream>>>(wskip, wts, 1, 64);

    k_stats64<<<NPTS / 256, 256, 0, stream>>>(feats, sum1, ss1);
    k_finalize<64><<<1, 64, 0, stream>>>(sum1, ss1, bn1_g, bn1_b, sc1, sh1);

    // normalize feats once -> bf16 (overwrites grid region, rulebook is done)
    k_norm1<<<NPTS * 64 / 8 / 256, 256, 0, stream>>>(feats, sc1, sh1, featsn);

    // conv1: direct-frag gather-GEMM, fused bn2 stats
    k_convd<64, ushort, 1><<<NPTS / 128, 256, 0, stream>>>(
        featsn, nbrT, wt1, out1, sum2, ss2);

    k_finalize<128><<<1, 128, 0, stream>>>(sum2, ss2, bn2_g, bn2_b, sc2, sh2);

    // normalize out1 in place
    k_norm2<<<NPTS * 128 / 8 / 256, 256, 0, stream>>>(out1, sc2, sh2);

    // conv2: direct-frag gather-GEMM, fused batch pool
    k_convd<128, float, 2><<<NPTS / 128, 256, 0, stream>>>(
        out1, nbrT, wt2, out, pooled, nullptr);

    // skip GEMM (out1/featsn dead): id = feats @ w_skip -> bf16 over out1
    k_conv<float, ushort, 64, 1, false, 0><<<NPTS / 128, 256, 0, stream>>>(
        feats, nullptr, nullptr, nullptr, wts, out1, nullptr, nullptr);

    k_se<<<1, 256, 0, stream>>>(pooled, fc1w, fc1b, fc2w, fc2b, se);
    k_final<<<NPTS * 128 / 1024, 256, 0, stream>>>(out, out1, se);
  } else {
    // fallback: previous verified pipeline (LDS-staged convs, transposed nbr)
    int* grid_i = (int*)p;
    ushort* out1 = (ushort*)p;

    hipMemsetAsync(grid_i, 0xFF, (size_t)BB * HH * WW * 4, stream);
    k_scatter<<<NPTS / 256, 256, 0, stream>>>(indices, grid_i);
    k_rulebook<<<NPTS / 256, 256, 0, stream>>>(indices, grid_i, nbrT);

    k_wprep<<<(9 * 64 * 128 + 255) / 256, 256, 0, stream>>>(w1, wt1, 9, 64);
    k_wprep<<<(9 * 128 * 128 + 255) / 256, 256, 0, stream>>>(w2, wt2, 9, 128);
    k_wprep<<<(64 * 128 + 255) / 256, 256, 0, stream>>>(wskip, wts, 1, 64);

    k_stats64<<<NPTS / 256, 256, 0, stream>>>(feats, sum1, ss1);
    k_finalize<64><<<1, 64, 0, stream>>>(sum1, ss1, bn1_g, bn1_b, sc1, sh1);

    k_conv<float, ushort, 64, 9, true, 1><<<NPTS / 128, 256, 0, stream>>>(
        feats, sc1, sh1, nbrT, wt1, out1, sum2, ss2);

    k_finalize<128><<<1, 128, 0, stream>>>(sum2, ss2, bn2_g, bn2_b, sc2, sh2);

    k_conv<ushort, float, 128, 9, true, 2><<<NPTS / 128, 256, 0, stream>>>(
        out1, sc2, sh2, nbrT, wt2, out, pooled, nullptr);

    k_conv<float, ushort, 64, 1, false, 0><<<NPTS / 128, 256, 0, stream>>>(
        feats, nullptr, nullptr, nullptr, wts, out1, nullptr, nullptr);

    k_se<<<1, 256, 0, stream>>>(pooled, fc1w, fc1b, fc2w, fc2b, se);
    k_final<<<NPTS * 128 / 1024, 256, 0, stream>>>(out, out1, se);
  }
}

// Round 4
// 689.094 us; speedup vs baseline: 1.0303x; 1.0303x over previous
//
#include <hip/hip_runtime.h>
#include <math.h>

#define NPTS 262144
#define BB 8
#define HH 512
#define WW 512
#define EPSV 1e-5f

typedef short short8v __attribute__((ext_vector_type(8)));
typedef short short4v __attribute__((ext_vector_type(4)));
typedef float float4v __attribute__((ext_vector_type(4)));
typedef unsigned short ushort;
typedef ushort ushort8v __attribute__((ext_vector_type(8)));

static __device__ __forceinline__ ushort f2bf(float f) {
  union { float f; unsigned u; } v;
  v.f = f;
  unsigned r = v.u + 0x7fffu + ((v.u >> 16) & 1u);  // round-to-nearest-even
  return (ushort)(r >> 16);
}

static __device__ __forceinline__ float bf2f(ushort h) {
  union { unsigned u; float f; } v;
  v.u = ((unsigned)h) << 16;
  return v.f;
}

// ---------------- rulebook (transposed: nbrT[tap][pt]) ----------------

__global__ __launch_bounds__(256) void k_scatter(const int* __restrict__ idx,
                                                 int* __restrict__ grid) {
  int i = blockIdx.x * 256 + threadIdx.x;
  int b = idx[i * 3 + 0], y = idx[i * 3 + 1], x = idx[i * 3 + 2];
  grid[(b * HH + y) * WW + x] = i;
}

__global__ __launch_bounds__(256) void k_rulebook(const int* __restrict__ idx,
                                                  const int* __restrict__ grid,
                                                  int* __restrict__ nbrT) {
  int i = blockIdx.x * 256 + threadIdx.x;
  int b = idx[i * 3 + 0], y = idx[i * 3 + 1], x = idx[i * 3 + 2];
  int t = 0;
  #pragma unroll
  for (int dy = -1; dy <= 1; ++dy) {
    #pragma unroll
    for (int dx = -1; dx <= 1; ++dx) {
      int ny = y + dy, nx = x + dx;
      int v = -1;
      if (ny >= 0 && ny < HH && nx >= 0 && nx < WW)
        v = grid[(b * HH + ny) * WW + nx];
      nbrT[(size_t)t * NPTS + i] = v;
      ++t;
    }
  }
}

// ---------------- batchnorm stats (feats, fp32, CI=64) ----------------

__global__ __launch_bounds__(256) void k_stats64(const float* __restrict__ x,
                                                 float* __restrict__ sum,
                                                 float* __restrict__ ssum) {
  __shared__ float red_s[4][64];
  __shared__ float red_q[4][64];
  const int tid = threadIdx.x;
  const int lane = tid & 63;
  const int wave = tid >> 6;
  const int c4 = lane & 15;
  const int rq = lane >> 4;
  long long base = (long long)blockIdx.x * 256;
  float s0 = 0.f, s1 = 0.f, s2 = 0.f, s3 = 0.f;
  float q0 = 0.f, q1 = 0.f, q2 = 0.f, q3 = 0.f;
  for (int r = wave * 4 + rq; r < 256; r += 16) {
    float4 v = *(const float4*)(x + (base + r) * 64 + c4 * 4);
    s0 += v.x; s1 += v.y; s2 += v.z; s3 += v.w;
    q0 += v.x * v.x; q1 += v.y * v.y; q2 += v.z * v.z; q3 += v.w * v.w;
  }
  s0 += __shfl_xor(s0, 16, 64); s0 += __shfl_xor(s0, 32, 64);
  s1 += __shfl_xor(s1, 16, 64); s1 += __shfl_xor(s1, 32, 64);
  s2 += __shfl_xor(s2, 16, 64); s2 += __shfl_xor(s2, 32, 64);
  s3 += __shfl_xor(s3, 16, 64); s3 += __shfl_xor(s3, 32, 64);
  q0 += __shfl_xor(q0, 16, 64); q0 += __shfl_xor(q0, 32, 64);
  q1 += __shfl_xor(q1, 16, 64); q1 += __shfl_xor(q1, 32, 64);
  q2 += __shfl_xor(q2, 16, 64); q2 += __shfl_xor(q2, 32, 64);
  q3 += __shfl_xor(q3, 16, 64); q3 += __shfl_xor(q3, 32, 64);
  if (rq == 0) {
    red_s[wave][c4 * 4 + 0] = s0; red_s[wave][c4 * 4 + 1] = s1;
    red_s[wave][c4 * 4 + 2] = s2; red_s[wave][c4 * 4 + 3] = s3;
    red_q[wave][c4 * 4 + 0] = q0; red_q[wave][c4 * 4 + 1] = q1;
    red_q[wave][c4 * 4 + 2] = q2; red_q[wave][c4 * 4 + 3] = q3;
  }
  __syncthreads();
  if (tid < 64) {
    float ts = red_s[0][tid] + red_s[1][tid] + red_s[2][tid] + red_s[3][tid];
    float tq = red_q[0][tid] + red_q[1][tid] + red_q[2][tid] + red_q[3][tid];
    atomicAdd(&sum[tid], ts);
    atomicAdd(&ssum[tid], tq);
  }
}

template <int CI>
__global__ void k_finalize(const float* __restrict__ sum, const float* __restrict__ ssum,
                           const float* __restrict__ gam, const float* __restrict__ bet,
                           float* __restrict__ sc, float* __restrict__ sh) {
  int c = threadIdx.x;
  if (c < CI) {
    float m = sum[c] * (1.f / NPTS);
    float v = ssum[c] * (1.f / NPTS) - m * m;
    float s = gam[c] * rsqrtf(v + EPSV);
    sc[c] = s;
    sh[c] = bet[c] - m * s;
  }
}

// ---------------- normalize passes (apply BN+ReLU once, not 9x) ----------------

__global__ __launch_bounds__(256) void k_norm1(const float* __restrict__ x,
                                               const float* __restrict__ sc,
                                               const float* __restrict__ sh,
                                               ushort* __restrict__ y) {
  long long i = ((long long)blockIdx.x * 256 + threadIdx.x) * 8;
  int c = (int)(i & 63);
  float4 a = *(const float4*)(x + i);
  float4 b = *(const float4*)(x + i + 4);
  float4 s0 = *(const float4*)(sc + c);
  float4 s1 = *(const float4*)(sc + c + 4);
  float4 h0 = *(const float4*)(sh + c);
  float4 h1 = *(const float4*)(sh + c + 4);
  ushort8v o;
  o[0] = f2bf(fmaxf(a.x * s0.x + h0.x, 0.f));
  o[1] = f2bf(fmaxf(a.y * s0.y + h0.y, 0.f));
  o[2] = f2bf(fmaxf(a.z * s0.z + h0.z, 0.f));
  o[3] = f2bf(fmaxf(a.w * s0.w + h0.w, 0.f));
  o[4] = f2bf(fmaxf(b.x * s1.x + h1.x, 0.f));
  o[5] = f2bf(fmaxf(b.y * s1.y + h1.y, 0.f));
  o[6] = f2bf(fmaxf(b.z * s1.z + h1.z, 0.f));
  o[7] = f2bf(fmaxf(b.w * s1.w + h1.w, 0.f));
  *(ushort8v*)(y + i) = o;
}

__global__ __launch_bounds__(256) void k_norm2(ushort* __restrict__ x,
                                               const float* __restrict__ sc,
                                               const float* __restrict__ sh) {
  long long i = ((long long)blockIdx.x * 256 + threadIdx.x) * 8;
  int c = (int)(i & 127);
  ushort8v v = *(const ushort8v*)(x + i);
  float4 s0 = *(const float4*)(sc + c);
  float4 s1 = *(const float4*)(sc + c + 4);
  float4 h0 = *(const float4*)(sh + c);
  float4 h1 = *(const float4*)(sh + c + 4);
  ushort8v o;
  o[0] = f2bf(fmaxf(bf2f(v[0]) * s0.x + h0.x, 0.f));
  o[1] = f2bf(fmaxf(bf2f(v[1]) * s0.y + h0.y, 0.f));
  o[2] = f2bf(fmaxf(bf2f(v[2]) * s0.z + h0.z, 0.f));
  o[3] = f2bf(fmaxf(bf2f(v[3]) * s0.w + h0.w, 0.f));
  o[4] = f2bf(fmaxf(bf2f(v[4]) * s1.x + h1.x, 0.f));
  o[5] = f2bf(fmaxf(bf2f(v[5]) * s1.y + h1.y, 0.f));
  o[6] = f2bf(fmaxf(bf2f(v[6]) * s1.z + h1.z, 0.f));
  o[7] = f2bf(fmaxf(bf2f(v[7]) * s1.w + h1.w, 0.f));
  *(ushort8v*)(x + i) = o;
}

// ---------------- weight prep: fp32 [taps][ci][128] -> bf16 [taps][128][ci] ----

__global__ __launch_bounds__(256) void k_wprep(const float* __restrict__ w,
                                               ushort* __restrict__ wt,
                                               int taps, int ci) {
  int i = blockIdx.x * 256 + threadIdx.x;
  int total = taps * ci * 128;
  if (i < total) {
    int t = i / (ci * 128);
    int rem = i - t * ci * 128;
    int c = rem >> 7;
    int o = rem & 127;
    wt[((size_t)t * 128 + o) * ci + c] = f2bf(w[i]);
  }
}

// ---------------- pipelined gather-GEMM conv ----------------
// Single 32KB(16KB) LDS A-tile, tap-level software pipeline:
//   iter k: issue gathers(k+1)->regs | MFMA(k) from LDS | sync | ds_write(k+1) | sync
// nbr ids prefetched 2 taps ahead. LDS XOR-swizzled (chunk ^= row&7) on both
// write and read -> conflict-free ds_read_b128. Each row gathered once per
// block (LDS shares it across the 2 consuming waves). B direct from global
// (32KB/tap weight tile, L1/L2-hot). blockIdx remapped so each XCD works one
// batch -> gather working set ~fits its private L2.
// EPI=1: fused bn-stats of stored bf16. EPI=2: fused batch pool.

template <int CI, typename DstT, int EPI>
__global__ __launch_bounds__(256) void k_convp(const ushort* __restrict__ src,
                                               const int* __restrict__ nbrT,
                                               const ushort* __restrict__ wt,
                                               DstT* __restrict__ dst,
                                               float* __restrict__ e0,
                                               float* __restrict__ e1) {
  constexpr int CHUNKS = CI / 8;       // 16B chunks per row (8 or 16)
  constexpr int RPI    = 64 / CHUNKS;  // rows per staging store (8 or 4)
  constexpr int NSTG   = 32 / RPI;     // staging stores per wave (4 or 8)
  __shared__ ushort As[128 * CI];      // 16KB (CI=64) / 32KB (CI=128)

  const int tid = threadIdx.x;
  int bidx = blockIdx.x;
  bidx = (bidx & 7) * ((NPTS / 128) / 8) + (bidx >> 3);  // XCD->batch affinity
  const int base = bidx * 128;
  const int lane = tid & 63;
  const int wave = tid >> 6;
  const int wm = wave & 1, wn = wave >> 1;
  const int m_base = wm * 64, n_base = wn * 64;
  const int fm = lane & 15;
  const int fq = lane >> 4;

  const int s_rl = lane / CHUNKS;        // staging local row
  const int s_c  = lane % CHUNKS;        // staging chunk (16B units)
  const int srow0 = wave * 32 + s_rl;

  float4v acc[4][4];
  #pragma unroll
  for (int i = 0; i < 4; ++i)
    #pragma unroll
    for (int j = 0; j < 4; ++j) acc[i][j] = (float4v){0.f, 0.f, 0.f, 0.f};

  int nr[2][NSTG];
  uint4 g[NSTG];

  // nbr ids for taps 0 and 1
  #pragma unroll
  for (int i = 0; i < NSTG; ++i)
    nr[0][i] = nbrT[base + srow0 + i * RPI];
  #pragma unroll
  for (int i = 0; i < NSTG; ++i)
    nr[1][i] = nbrT[(size_t)NPTS + base + srow0 + i * RPI];

  // stage tap 0
  #pragma unroll
  for (int i = 0; i < NSTG; ++i) {
    int nid = nr[0][i];
    uint4 gv = {0u, 0u, 0u, 0u};
    if (nid >= 0) gv = *(const uint4*)(src + (size_t)nid * CI + s_c * 8);
    g[i] = gv;
  }
  #pragma unroll
  for (int i = 0; i < NSTG; ++i) {
    int row = srow0 + i * RPI;
    *(uint4*)(&As[row * CI + ((s_c ^ (row & 7)) << 3)]) = g[i];
  }
  __syncthreads();

  #pragma unroll
  for (int k = 0; k < 9; ++k) {
    // issue next tap's gathers (latency hides under this tap's MFMAs)
    if (k < 8) {
      #pragma unroll
      for (int i = 0; i < NSTG; ++i) {
        int nid = nr[(k + 1) & 1][i];
        uint4 gv = {0u, 0u, 0u, 0u};
        if (nid >= 0) gv = *(const uint4*)(src + (size_t)nid * CI + s_c * 8);
        g[i] = gv;
      }
    }
    // prefetch nbr ids 2 taps ahead
    if (k < 7) {
      #pragma unroll
      for (int i = 0; i < NSTG; ++i)
        nr[k & 1][i] = nbrT[(size_t)(k + 2) * NPTS + base + srow0 + i * RPI];
    }

    // ---- MFMA tap k from LDS (swizzled reads) ----
    const ushort* wrow = wt + ((size_t)k * 128 + n_base + fm) * CI + fq * 8;
    #pragma unroll
    for (int kc = 0; kc < CI / 32; ++kc) {
      short8v af[4], bfr[4];
      #pragma unroll
      for (int mi = 0; mi < 4; ++mi) {
        int R = m_base + mi * 16 + fm;
        af[mi] = *(const short8v*)(&As[R * CI + (((kc * 4 + fq) ^ (fm & 7)) << 3)]);
      }
      #pragma unroll
      for (int ni = 0; ni < 4; ++ni)
        bfr[ni] = *(const short8v*)(wrow + ni * 16 * CI + kc * 32);
      #pragma unroll
      for (int mi = 0; mi < 4; ++mi)
        #pragma unroll
        for (int ni = 0; ni < 4; ++ni)
          acc[mi][ni] = __builtin_amdgcn_mfma_f32_16x16x32_bf16(af[mi], bfr[ni], acc[mi][ni], 0, 0, 0);
    }

    if (k < 8) {
      __syncthreads();  // all waves done reading tap k
      #pragma unroll
      for (int i = 0; i < NSTG; ++i) {
        int row = srow0 + i * RPI;
        *(uint4*)(&As[row * CI + ((s_c ^ (row & 7)) << 3)]) = g[i];
      }
      __syncthreads();  // tap k+1 visible
    }
  }

  // ---- epilogue: C/D layout col=lane&15, row=quad*4+reg ----
  float es[4], ess[4];
  if constexpr (EPI) {
    #pragma unroll
    for (int ni = 0; ni < 4; ++ni) { es[ni] = 0.f; ess[ni] = 0.f; }
  }
  #pragma unroll
  for (int mi = 0; mi < 4; ++mi) {
    #pragma unroll
    for (int ni = 0; ni < 4; ++ni) {
      int pt = base + m_base + mi * 16 + fq * 4;
      int co = n_base + ni * 16 + fm;
      float4v c = acc[mi][ni];
      #pragma unroll
      for (int r = 0; r < 4; ++r) {
        if constexpr (sizeof(DstT) == 4) {
          ((float*)dst)[(size_t)(pt + r) * 128 + co] = c[r];
          if constexpr (EPI == 2) es[ni] += c[r];
        } else {
          ushort h = f2bf(c[r]);
          ((ushort*)dst)[(size_t)(pt + r) * 128 + co] = h;
          if constexpr (EPI == 1) {
            float v = bf2f(h);
            es[ni] += v;
            ess[ni] += v * v;
          }
        }
      }
    }
  }

  if constexpr (EPI) {
    #pragma unroll
    for (int ni = 0; ni < 4; ++ni) {
      float s = es[ni];
      s += __shfl_xor(s, 16, 64);
      s += __shfl_xor(s, 32, 64);
      float q = 0.f;
      if constexpr (EPI == 1) {
        q = ess[ni];
        q += __shfl_xor(q, 16, 64);
        q += __shfl_xor(q, 32, 64);
      }
      if (fq == 0) {
        int co = n_base + ni * 16 + fm;
        if constexpr (EPI == 1) {
          atomicAdd(&e0[co], s);
          atomicAdd(&e1[co], q);
        } else {
          int b = base >> 15;
          atomicAdd(&e0[b * 128 + co], s);
        }
      }
    }
  }
}

// ---------------- legacy LDS-staged conv (fallback path + skip GEMM) ----------------

template <typename SrcT, typename DstT, int CI, int TAPS, bool ACT, int EPI>
__global__ __launch_bounds__(256) void k_conv(const SrcT* __restrict__ src,
                                              const float* __restrict__ scale,
                                              const float* __restrict__ shift,
                                              const int* __restrict__ nbrT,
                                              const ushort* __restrict__ wt,
                                              DstT* __restrict__ dst,
                                              float* __restrict__ e0,
                                              float* __restrict__ e1) {
  constexpr int SA = CI + 8;
  __shared__ ushort As[128 * SA];
  __shared__ ushort Bs[128 * SA];
  __shared__ float s_sc[CI], s_sh[CI];

  const int tid = threadIdx.x;
  const int base = blockIdx.x * 128;
  const int lane = tid & 63;
  const int wave = tid >> 6;
  const int wm = wave & 1, wn = wave >> 1;
  const int m_base = wm * 64, n_base = wn * 64;
  const int fm = lane & 15;
  const int fq = lane >> 4;

  if constexpr (ACT) {
    for (int c = tid; c < CI; c += 256) {
      s_sc[c] = scale[c];
      s_sh[c] = shift[c];
    }
  }
  __syncthreads();

  float4v acc[4][4];
  #pragma unroll
  for (int i = 0; i < 4; ++i)
    #pragma unroll
    for (int j = 0; j < 4; ++j) acc[i][j] = (float4v){0.f, 0.f, 0.f, 0.f};

  const int srow_i = tid >> 1;
  const int shalf = tid & 1;
  const int c0 = shalf * (CI / 2);

  for (int k = 0; k < TAPS; ++k) {
    if (k) __syncthreads();

    int nid;
    if constexpr (TAPS == 1) {
      nid = base + srow_i;
    } else {
      nid = nbrT[(size_t)k * NPTS + base + srow_i];
    }
    ushort* arow = &As[srow_i * SA + c0];
    if (nid >= 0) {
      const SrcT* gsrc = src + (size_t)nid * CI + c0;
      if constexpr (sizeof(SrcT) == 4) {
        #pragma unroll
        for (int j = 0; j < CI / 2; j += 4) {
          float4 v = *(const float4*)((const float*)gsrc + j);
          if constexpr (ACT) {
            int c = c0 + j;
            v.x = fmaxf(v.x * s_sc[c + 0] + s_sh[c + 0], 0.f);
            v.y = fmaxf(v.y * s_sc[c + 1] + s_sh[c + 1], 0.f);
            v.z = fmaxf(v.z * s_sc[c + 2] + s_sh[c + 2], 0.f);
            v.w = fmaxf(v.w * s_sc[c + 3] + s_sh[c + 3], 0.f);
          }
          short4v o = {(short)f2bf(v.x), (short)f2bf(v.y), (short)f2bf(v.z), (short)f2bf(v.w)};
          *(short4v*)(arow + j) = o;
        }
      } else {
        #pragma unroll
        for (int j = 0; j < CI / 2; j += 8) {
          ushort8v raw = *(const ushort8v*)((const ushort*)gsrc + j);
          short8v o;
          #pragma unroll
          for (int e = 0; e < 8; ++e) {
            float f = bf2f(raw[e]);
            if constexpr (ACT) {
              int c = c0 + j + e;
              f = fmaxf(f * s_sc[c] + s_sh[c], 0.f);
            }
            o[e] = (short)f2bf(f);
          }
          *(short8v*)(arow + j) = o;
        }
      }
    } else {
      #pragma unroll
      for (int j = 0; j < CI / 2; j += 4)
        *(short4v*)(arow + j) = (short4v){0, 0, 0, 0};
    }

    {
      const ushort* wrow = wt + ((size_t)k * 128 + srow_i) * CI + c0;
      ushort* brow = &Bs[srow_i * SA + c0];
      #pragma unroll
      for (int j = 0; j < CI / 2; j += 8)
        *(uint4*)(brow + j) = *(const uint4*)(wrow + j);
    }
    __syncthreads();

    #pragma unroll
    for (int kc = 0; kc < CI / 32; ++kc) {
      short8v af[4], bf[4];
      #pragma unroll
      for (int mi = 0; mi < 4; ++mi)
        af[mi] = *(const short8v*)(&As[(m_base + mi * 16 + fm) * SA + kc * 32 + fq * 8]);
      #pragma unroll
      for (int ni = 0; ni < 4; ++ni)
        bf[ni] = *(const short8v*)(&Bs[(n_base + ni * 16 + fm) * SA + kc * 32 + fq * 8]);
      #pragma unroll
      for (int mi = 0; mi < 4; ++mi)
        #pragma unroll
        for (int ni = 0; ni < 4; ++ni)
          acc[mi][ni] = __builtin_amdgcn_mfma_f32_16x16x32_bf16(af[mi], bf[ni], acc[mi][ni], 0, 0, 0);
    }
  }

  float es[4], ess[4];
  if constexpr (EPI) {
    #pragma unroll
    for (int ni = 0; ni < 4; ++ni) { es[ni] = 0.f; ess[ni] = 0.f; }
  }
  #pragma unroll
  for (int mi = 0; mi < 4; ++mi) {
    #pragma unroll
    for (int ni = 0; ni < 4; ++ni) {
      int pt = base + m_base + mi * 16 + fq * 4;
      int co = n_base + ni * 16 + fm;
      float4v c = acc[mi][ni];
      #pragma unroll
      for (int r = 0; r < 4; ++r) {
        if constexpr (sizeof(DstT) == 4) {
          ((float*)dst)[(size_t)(pt + r) * 128 + co] = c[r];
          if constexpr (EPI == 2) es[ni] += c[r];
        } else {
          ushort h = f2bf(c[r]);
          ((ushort*)dst)[(size_t)(pt + r) * 128 + co] = h;
          if constexpr (EPI == 1) {
            float v = bf2f(h);
            es[ni] += v;
            ess[ni] += v * v;
          }
        }
      }
    }
  }

  if constexpr (EPI) {
    #pragma unroll
    for (int ni = 0; ni < 4; ++ni) {
      float s = es[ni];
      s += __shfl_xor(s, 16, 64);
      s += __shfl_xor(s, 32, 64);
      float q = 0.f;
      if constexpr (EPI == 1) {
        q = ess[ni];
        q += __shfl_xor(q, 16, 64);
        q += __shfl_xor(q, 32, 64);
      }
      if (fq == 0) {
        int co = n_base + ni * 16 + fm;
        if constexpr (EPI == 1) {
          atomicAdd(&e0[co], s);
          atomicAdd(&e1[co], q);
        } else {
          int b = base >> 15;
          atomicAdd(&e0[b * 128 + co], s);
        }
      }
    }
  }
}

// ---------------- SE / final ----------------

__global__ __launch_bounds__(256) void k_se(const float* __restrict__ pooled,
                                            const float* __restrict__ fc1w,
                                            const float* __restrict__ fc1b,
                                            const float* __restrict__ fc2w,
                                            const float* __restrict__ fc2b,
                                            float* __restrict__ se) {
  __shared__ float h[8][32];
  int tid = threadIdx.x;
  int b = tid >> 5, j = tid & 31;
  float s = fc1b[j];
  for (int c = 0; c < 128; ++c)
    s += pooled[b * 128 + c] * (1.f / 32768.f) * fc1w[j * 128 + c];
  h[b][j] = fmaxf(s, 0.f);
  __syncthreads();
  for (int t = tid; t < 1024; t += 256) {
    int bb = t >> 7, c = t & 127;
    float s2 = fc2b[c];
    #pragma unroll
    for (int jj = 0; jj < 32; ++jj) s2 += h[bb][jj] * fc2w[c * 32 + jj];
    se[t] = 1.f / (1.f + expf(-s2));
  }
}

__global__ __launch_bounds__(256) void k_final(float* __restrict__ out,
                                               const ushort* __restrict__ id,
                                               const float* __restrict__ se) {
  long long i = ((long long)blockIdx.x * 256 + threadIdx.x) * 4;
  int co = (int)(i & 127);
  long long rowi = i >> 7;
  int b = (int)(rowi >> 15);
  float4 o = *(const float4*)(out + i);
  ushort dh[4];
  *(uint2*)dh = *(const uint2*)(id + i);
  float4 s = *(const float4*)(se + b * 128 + co);
  o.x = o.x * s.x + bf2f(dh[0]);
  o.y = o.y * s.y + bf2f(dh[1]);
  o.z = o.z * s.z + bf2f(dh[2]);
  o.w = o.w * s.w + bf2f(dh[3]);
  *(float4*)(out + i) = o;
}

// ---------------- launch ----------------

extern "C" void kernel_launch(void* const* d_in, const int* in_sizes, int n_in,
                              void* d_out, int out_size, void* d_ws, size_t ws_size,
                              hipStream_t stream) {
  const float* feats = (const float*)d_in[0];
  const int* indices = (const int*)d_in[1];
  const float* bn1_g = (const float*)d_in[2];
  const float* bn1_b = (const float*)d_in[3];
  const float* w1    = (const float*)d_in[4];
  const float* bn2_g = (const float*)d_in[5];
  const float* bn2_b = (const float*)d_in[6];
  const float* w2    = (const float*)d_in[7];
  const float* fc1w  = (const float*)d_in[8];
  const float* fc1b  = (const float*)d_in[9];
  const float* fc2w  = (const float*)d_in[10];
  const float* fc2b  = (const float*)d_in[11];
  const float* wskip = (const float*)d_in[12];
  float* out = (float*)d_out;

  char* p = (char*)d_ws;
  int* nbrT = (int*)p;      p += (size_t)NPTS * 9 * 4;        // 9.44 MB
  float* stats = (float*)p; p += 4096 * 4;                    // 16 KB
  ushort* wt1 = (ushort*)p; p += (size_t)9 * 128 * 64 * 2;    // 144 KB
  ushort* wt2 = (ushort*)p; p += (size_t)9 * 128 * 128 * 2;   // 288 KB
  ushort* wts = (ushort*)p; p += (size_t)128 * 64 * 2;        // 16 KB
  p = (char*)(((size_t)p + 255) & ~(size_t)255);

  float* sum1 = stats, *ss1 = stats + 64, *sc1 = stats + 128, *sh1 = stats + 192;
  float* sum2 = stats + 256, *ss2 = stats + 384, *sc2 = stats + 512, *sh2 = stats + 640;
  float* pooled = stats + 768;
  float* se = stats + 1792;

  // big path needs: region1 = max(grid 8MB, featsn 33.5MB) + out1 67MB
  size_t fixed = (size_t)(p - (char*)d_ws);
  size_t need_new = fixed + (size_t)NPTS * 64 * 2 + (size_t)NPTS * 128 * 2;
  bool big = ws_size >= need_new;

  hipMemsetAsync(stats, 0, 4096 * 4, stream);

  if (big) {
    // region1: first serves as grid (8MB), later as featsn (33.5MB bf16)
    int* grid_i = (int*)p;
    ushort* featsn = (ushort*)p;
    ushort* out1 = (ushort*)(p + (size_t)NPTS * 64 * 2);  // also reused as id

    hipMemsetAsync(grid_i, 0xFF, (size_t)BB * HH * WW * 4, stream);
    k_scatter<<<NPTS / 256, 256, 0, stream>>>(indices, grid_i);
    k_rulebook<<<NPTS / 256, 256, 0, stream>>>(indices, grid_i, nbrT);

    k_wprep<<<(9 * 64 * 128 + 255) / 256, 256, 0, stream>>>(w1, wt1, 9, 64);
    k_wprep<<<(9 * 128 * 128 + 255) / 256, 256, 0, stream>>>(w2, wt2, 9, 128);
    k_wprep<<<(64 * 128 + 255) / 256, 256, 0, stream>>>(wskip, wts, 1, 64);

    k_stats64<<<NPTS / 256, 256, 0, stream>>>(feats, sum1, ss1);
    k_finalize<64><<<1, 64, 0, stream>>>(sum1, ss1, bn1_g, bn1_b, sc1, sh1);

    // normalize feats once -> bf16 (overwrites grid region, rulebook is done)
    k_norm1<<<NPTS * 64 / 8 / 256, 256, 0, stream>>>(feats, sc1, sh1, featsn);

    // conv1: pipelined gather-GEMM, fused bn2 stats
    k_convp<64, ushort, 1><<<NPTS / 128, 256, 0, stream>>>(
        featsn, nbrT, wt1, out1, sum2, ss2);

    k_finalize<128><<<1, 128, 0, stream>>>(sum2, ss2, bn2_g, bn2_b, sc2, sh2);

    // normalize out1 in place
    k_norm2<<<NPTS * 128 / 8 / 256, 256, 0, stream>>>(out1, sc2, sh2);

    // conv2: pipelined gather-GEMM, fused batch pool
    k_convp<128, float, 2><<<NPTS / 128, 256, 0, stream>>>(
        out1, nbrT, wt2, out, pooled, nullptr);

    // skip GEMM (out1/featsn dead): id = feats @ w_skip -> bf16 over out1
    k_conv<float, ushort, 64, 1, false, 0><<<NPTS / 128, 256, 0, stream>>>(
        feats, nullptr, nullptr, nullptr, wts, out1, nullptr, nullptr);

    k_se<<<1, 256, 0, stream>>>(pooled, fc1w, fc1b, fc2w, fc2b, se);
    k_final<<<NPTS * 128 / 1024, 256, 0, stream>>>(out, out1, se);
  } else {
    // fallback: round-1-verified pipeline (LDS-staged convs, transposed nbr)
    int* grid_i = (int*)p;
    ushort* out1 = (ushort*)p;

    hipMemsetAsync(grid_i, 0xFF, (size_t)BB * HH * WW * 4, stream);
    k_scatter<<<NPTS / 256, 256, 0, stream>>>(indices, grid_i);
    k_rulebook<<<NPTS / 256, 256, 0, stream>>>(indices, grid_i, nbrT);

    k_wprep<<<(9 * 64 * 128 + 255) / 256, 256, 0, stream>>>(w1, wt1, 9, 64);
    k_wprep<<<(9 * 128 * 128 + 255) / 256, 256, 0, stream>>>(w2, wt2, 9, 128);
    k_wprep<<<(64 * 128 + 255) / 256, 256, 0, stream>>>(wskip, wts, 1, 64);

    k_stats64<<<NPTS / 256, 256, 0, stream>>>(feats, sum1, ss1);
    k_finalize<64><<<1, 64, 0, stream>>>(sum1, ss1, bn1_g, bn1_b, sc1, sh1);

    k_conv<float, ushort, 64, 9, true, 1><<<NPTS / 128, 256, 0, stream>>>(
        feats, sc1, sh1, nbrT, wt1, out1, sum2, ss2);

    k_finalize<128><<<1, 128, 0, stream>>>(sum2, ss2, bn2_g, bn2_b, sc2, sh2);

    k_conv<ushort, float, 128, 9, true, 2><<<NPTS / 128, 256, 0, stream>>>(
        out1, sc2, sh2, nbrT, wt2, out, pooled, nullptr);

    k_conv<float, ushort, 64, 1, false, 0><<<NPTS / 128, 256, 0, stream>>>(
        feats, nullptr, nullptr, nullptr, wts, out1, nullptr, nullptr);

    k_se<<<1, 256, 0, stream>>>(pooled, fc1w, fc1b, fc2w, fc2b, se);
    k_final<<<NPTS * 128 / 1024, 256, 0, stream>>>(out, out1, se);
  }
}